// Round 8
// baseline (684.111 us; speedup 1.0000x reference)
//
#include <hip/hip_runtime.h>

// ---------------------------------------------------------------------------
// HeteroTripartiteGCN, round 8: leaner sort pipeline.
//   1) fused transforms (fp32 -> bf16 tables, one kernel)
//   2) bhist: per-chunk 666-bin LDS hist -> chunkCnt[chunk][bucket] (1.3MB)
//   3) chunkscan: per-bucket prefix over chunks (in-place) + bucketTotal
//   4) bscan: 666-entry exclusive scan -> bbase
//   5) bucketize (single pass now): key2[pos]=row_local<<1|rel (2B),
//      payload[pos]=col<<15|bf16(val)&0x7FFF (4B), cursors from
//      bbase+chunkCnt -- no re-hist, no memset
//   6) finesort: block/bucket, count pass reads ONLY key2 (16MB), scatter
//      moves ready payload into row-sorted arena; writes rowptr p2
//   7) gather: wave/row, half-wave/edge, bf16 pairs, fused ReLU
// d_out: [msg_u | msg_v | msg_f] fp32, every row written exactly once.
// ---------------------------------------------------------------------------

#define TDIM 64
#define EPB  16384

struct Rel {
    const int* rows; const int* cols; const float* vals;
    int n, chunk0, boff, shift, srcflag;
};
struct RelPack { Rel r[6]; };

struct TPack {
    const float* X[3]; const float* W1[3]; const float* W2[3];
    unsigned short* Y1[3]; unsigned short* Y2[3];
    int N[3]; int c0[3];
};

struct GatherPack {
    const unsigned* srcA[3]; const unsigned* srcB[3];
    int n0, n1;   // NU, NU+NV
};

__device__ __forceinline__ unsigned short f2bf(float f) {
    union { float f; unsigned u; } c; c.f = f;
    unsigned r = c.u + 0x7FFFu + ((c.u >> 16) & 1u);  // RNE
    return (unsigned short)(r >> 16);
}
__device__ __forceinline__ float bflo(unsigned x) { return __uint_as_float(x << 16); }
__device__ __forceinline__ float bfhi(unsigned x) { return __uint_as_float(x & 0xFFFF0000u); }
__device__ __forceinline__ float pval(unsigned p) {
    return __uint_as_float((p & 0x7FFFu) << 16);     // bf16 val, sign==0
}

// ---------------- fused dense transforms (fp32 in, bf16 out) ----------------
__global__ __launch_bounds__(256) void transform_fused_kernel(TPack T)
{
    __shared__ float xsT[64 * 68];
    __shared__ float w1s[64 * 64];
    __shared__ float w2s[64 * 64];

    int t = 0;
    if ((int)blockIdx.x >= T.c0[1]) t = 1;
    if ((int)blockIdx.x >= T.c0[2]) t = 2;
    const float* __restrict__ X  = T.X[t];
    const float* __restrict__ W1 = T.W1[t];
    const float* __restrict__ W2 = T.W2[t];
    unsigned short* __restrict__ Y1 = T.Y1[t];
    unsigned short* __restrict__ Y2 = T.Y2[t];
    const int N    = T.N[t];
    const int row0 = (blockIdx.x - T.c0[t]) * 64;
    const int tid  = threadIdx.x;

    for (int i = tid * 4; i < 4096; i += 256 * 4) {
        *(float4*)&w1s[i] = *(const float4*)&W1[i];
        *(float4*)&w2s[i] = *(const float4*)&W2[i];
    }
    {
        const int r  = tid >> 2;
        const int c0 = (tid & 3) * 16;
        const int gr = row0 + r;
        #pragma unroll
        for (int cc = 0; cc < 16; cc += 4) {
            const int c = c0 + cc;
            float4 v = make_float4(0.f, 0.f, 0.f, 0.f);
            if (gr < N) v = *(const float4*)&X[(size_t)gr * TDIM + c];
            xsT[(c + 0) * 68 + r] = v.x;
            xsT[(c + 1) * 68 + r] = v.y;
            xsT[(c + 2) * 68 + r] = v.z;
            xsT[(c + 3) * 68 + r] = v.w;
        }
    }
    __syncthreads();

    const int tx = tid & 15;
    const int ty = tid >> 4;
    float a1[4][4] = {{0.f}}, a2[4][4] = {{0.f}};

    #pragma unroll 8
    for (int k = 0; k < 64; ++k) {
        const float4 xv = *(const float4*)&xsT[k * 68 + ty * 4];
        const float4 w1 = *(const float4*)&w1s[k * 64 + tx * 4];
        const float4 w2 = *(const float4*)&w2s[k * 64 + tx * 4];
        const float xr[4] = {xv.x, xv.y, xv.z, xv.w};
        const float c1[4] = {w1.x, w1.y, w1.z, w1.w};
        const float c2[4] = {w2.x, w2.y, w2.z, w2.w};
        #pragma unroll
        for (int r = 0; r < 4; ++r)
            #pragma unroll
            for (int c = 0; c < 4; ++c) {
                a1[r][c] = fmaf(xr[r], c1[c], a1[r][c]);
                a2[r][c] = fmaf(xr[r], c2[c], a2[r][c]);
            }
    }
    #pragma unroll
    for (int r = 0; r < 4; ++r) {
        const int gr = row0 + ty * 4 + r;
        if (gr < N) {
            ushort4 o1, o2;
            o1.x = f2bf(a1[r][0]); o1.y = f2bf(a1[r][1]);
            o1.z = f2bf(a1[r][2]); o1.w = f2bf(a1[r][3]);
            o2.x = f2bf(a2[r][0]); o2.y = f2bf(a2[r][1]);
            o2.z = f2bf(a2[r][2]); o2.w = f2bf(a2[r][3]);
            ((ushort4*)Y1)[(size_t)gr * 16 + tx] = o1;
            ((ushort4*)Y2)[(size_t)gr * 16 + tx] = o2;
        }
    }
}

__device__ __forceinline__ int find_rel(const RelPack& P, int chunk) {
    int ri = 0;
    if (chunk >= P.r[1].chunk0) ri = 1;
    if (chunk >= P.r[2].chunk0) ri = 2;
    if (chunk >= P.r[3].chunk0) ri = 3;
    if (chunk >= P.r[4].chunk0) ri = 4;
    if (chunk >= P.r[5].chunk0) ri = 5;
    return ri;
}

// ---------------- bhist: per-chunk 666-bin histogram ----------------
__global__ __launch_bounds__(512) void bhist_kernel(
    RelPack P, int* __restrict__ chunkCnt, int NB)
{
    __shared__ int cnt[1024];
    const int tid = threadIdx.x;
    for (int t = tid; t < NB; t += 512) cnt[t] = 0;
    __syncthreads();

    const int chunk = blockIdx.x;
    const int ri = find_rel(P, chunk);
    const Rel M = P.r[ri];
    const int i0 = (chunk - M.chunk0) * EPB;
    #pragma unroll
    for (int k = 0; k < EPB / 512; ++k) {
        const int i = i0 + tid + k * 512;
        if (i < M.n) atomicAdd(&cnt[M.boff + (M.rows[i] >> M.shift)], 1);
    }
    __syncthreads();
    for (int t = tid; t < NB; t += 512)
        chunkCnt[(size_t)chunk * NB + t] = cnt[t];
}

// ---------------- chunkscan: per-bucket prefix over chunks (in place) ------
__global__ __launch_bounds__(256) void chunkscan_kernel(
    int* __restrict__ chunkCnt, int* __restrict__ bucketTotal,
    int NB, int nchunks)
{
    __shared__ int sh[256];
    __shared__ int carry;
    const int b = blockIdx.x;
    const int t = threadIdx.x;
    if (t == 0) carry = 0;
    __syncthreads();
    for (int c0 = 0; c0 < nchunks; c0 += 256) {
        const int c = c0 + t;
        const int v = (c < nchunks) ? chunkCnt[(size_t)c * NB + b] : 0;
        sh[t] = v;
        __syncthreads();
        for (int off = 1; off < 256; off <<= 1) {
            const int x = (t >= off) ? sh[t - off] : 0;
            __syncthreads();
            sh[t] += x;
            __syncthreads();
        }
        const int excl = carry + sh[t] - v;
        if (c < nchunks) chunkCnt[(size_t)c * NB + b] = excl;
        __syncthreads();
        if (t == 0) carry += sh[255];
        __syncthreads();
    }
    if (t == 0) bucketTotal[b] = carry;
}

// ---------------- bscan: 666-entry exclusive scan ----------------
__global__ __launch_bounds__(256) void bscan_kernel(
    const int* __restrict__ bucketTotal, int* __restrict__ bbase, int NB)
{
    __shared__ int sh[256];
    __shared__ int carry;
    const int t = threadIdx.x;
    if (t == 0) carry = 0;
    __syncthreads();
    for (int b0 = 0; b0 < NB; b0 += 256) {
        const int idx = b0 + t;
        const int c = (idx < NB) ? bucketTotal[idx] : 0;
        sh[t] = c;
        __syncthreads();
        for (int off = 1; off < 256; off <<= 1) {
            const int x = (t >= off) ? sh[t - off] : 0;
            __syncthreads();
            sh[t] += x;
            __syncthreads();
        }
        const int cbase = carry;
        if (idx < NB) bbase[idx] = cbase + sh[t] - c;
        __syncthreads();
        if (t == 0) carry = cbase + sh[255];
        __syncthreads();
    }
    if (t == 0) bbase[NB] = carry;
}

// ---------------- bucketize: single pass, split key/payload ----------------
__global__ __launch_bounds__(512) void bucketize_kernel(
    RelPack P, const int* __restrict__ bbase, const int* __restrict__ chunkExcl,
    unsigned short* __restrict__ key2, unsigned* __restrict__ payload, int NB)
{
    __shared__ int cur[1024];
    const int tid   = threadIdx.x;
    const int chunk = blockIdx.x;
    for (int t = tid; t < NB; t += 512)
        cur[t] = bbase[t] + chunkExcl[(size_t)chunk * NB + t];
    __syncthreads();

    const int ri = find_rel(P, chunk);
    const Rel M = P.r[ri];
    const int i0 = (chunk - M.chunk0) * EPB;
    const int mask = (1 << M.shift) - 1;
    const unsigned flag = (unsigned)M.srcflag;

    #pragma unroll
    for (int k = 0; k < EPB / 512; ++k) {
        const int i = i0 + tid + k * 512;
        if (i < M.n) {
            const int row = M.rows[i];
            const int b   = M.boff + (row >> M.shift);
            const int pos = atomicAdd(&cur[b], 1);
            key2[pos]    = (unsigned short)((unsigned)((row & mask) << 1) | flag);
            payload[pos] = ((unsigned)M.cols[i] << 15) |
                           ((unsigned)f2bf(M.vals[i]) & 0x7FFFu);
        }
    }
}

// ---------------- finesort: block per bucket -> rowptr p2 + arena ----------
__global__ __launch_bounds__(512) void finesort_kernel(
    const unsigned short* __restrict__ key2, const unsigned* __restrict__ payload,
    const int* __restrict__ bbase, int* __restrict__ p2,
    unsigned* __restrict__ arena,
    int nbU, int nbV, int NU, int NV, int NF, int NB, int ntot_rows)
{
    __shared__ int cnt[512];
    __shared__ int sh[512];

    const int b   = blockIdx.x;
    const int tid = threadIdx.x;

    int t, lb, rowbase;
    if (b < nbU)              { t = 0; lb = b;              rowbase = 0; }
    else if (b < nbU + nbV)   { t = 1; lb = b - nbU;        rowbase = NU; }
    else                      { t = 2; lb = b - nbU - nbV;  rowbase = NU + NV; }
    const int shift     = (t == 2) ? 6 : 8;
    const int Ntype     = (t == 0) ? NU : (t == 1) ? NV : NF;
    const int row_start = lb << shift;
    const int nrows     = min(1 << shift, Ntype - row_start);
    const int nbins     = (1 << shift) * 2;
    const int grow0     = rowbase + row_start;

    if (tid < nbins) cnt[tid] = 0;
    __syncthreads();

    const int s = bbase[b];
    const int e = bbase[b + 1];

    // pass 1: count (key stream only, 2B/rec)
    for (int j = s + tid; j < e; j += 512)
        atomicAdd(&cnt[key2[j]], 1);
    __syncthreads();

    // exclusive scan over nbins (<=512), 1 bin/thread
    const int v = (tid < nbins) ? cnt[tid] : 0;
    sh[tid] = v;
    __syncthreads();
    for (int off = 1; off < 512; off <<= 1) {
        const int x = (tid >= off) ? sh[tid - off] : 0;
        __syncthreads();
        sh[tid] += x;
        __syncthreads();
    }
    const int excl = sh[tid] - v;
    if (tid < nbins) cnt[tid] = excl;          // cursors
    if (tid < nrows * 2) p2[2 * grow0 + tid] = s + excl;
    if (b == NB - 1 && tid == 0) p2[2 * ntot_rows] = e;
    __syncthreads();

    // pass 2: move ready payload into row-sorted arena (bucket segment L2-hot)
    for (int j = s + tid; j < e; j += 512) {
        const int bin = key2[j];
        const int pos = s + atomicAdd(&cnt[bin], 1);
        arena[pos] = payload[j];
    }
}

// ---------------- gather: wave per row, half-wave per edge, ReLU -----------
__global__ __launch_bounds__(256) void gather_all_kernel(
    const int* __restrict__ p2, const unsigned* __restrict__ arena,
    GatherPack G, float* __restrict__ out, int nrow_total)
{
    const int wid  = (blockIdx.x * 256 + threadIdx.x) >> 6;
    const int lane = threadIdx.x & 63;
    const int half = lane >> 5;
    const int sub  = lane & 31;
    if (wid >= nrow_total) return;

    int seg = 0;
    if (wid >= G.n1)      seg = 2;
    else if (wid >= G.n0) seg = 1;

    const int pa = p2[2 * wid];
    const int pm = p2[2 * wid + 1];
    const int pe = p2[2 * wid + 2];

    float accx = 0.f, accy = 0.f;

    #pragma unroll
    for (int hh = 0; hh < 2; ++hh) {
        const unsigned* __restrict__ src = hh ? G.srcB[seg] : G.srcA[seg];
        const int s = hh ? pm : pa;
        const int e = hh ? pe : pm;
        int j = s;
        for (; j + 8 <= e; j += 8) {           // 8 edges: 4 per half-wave
            unsigned cv[4], x[4];
            #pragma unroll
            for (int q = 0; q < 4; ++q) cv[q] = arena[j + 2 * q + half];
            #pragma unroll
            for (int q = 0; q < 4; ++q)
                x[q] = src[(size_t)(cv[q] >> 15) * 32 + sub];
            #pragma unroll
            for (int q = 0; q < 4; ++q) {
                const float w = pval(cv[q]);
                accx = fmaf(w, bflo(x[q]), accx);
                accy = fmaf(w, bfhi(x[q]), accy);
            }
        }
        for (; j + 2 <= e; j += 2) {
            const unsigned cv = arena[j + half];
            const unsigned x  = src[(size_t)(cv >> 15) * 32 + sub];
            const float w = pval(cv);
            accx = fmaf(w, bflo(x), accx);
            accy = fmaf(w, bfhi(x), accy);
        }
        if (half == 0 && j < e) {
            const unsigned cv = arena[j];
            const unsigned x  = src[(size_t)(cv >> 15) * 32 + sub];
            const float w = pval(cv);
            accx = fmaf(w, bflo(x), accx);
            accy = fmaf(w, bfhi(x), accy);
        }
    }

    accx += __shfl_xor(accx, 32, 64);
    accy += __shfl_xor(accy, 32, 64);
    if (half == 0) {
        float2 o = make_float2(fmaxf(accx, 0.f), fmaxf(accy, 0.f));
        ((float2*)out)[(size_t)wid * 32 + sub] = o;
    }
}

// ---------------------------------------------------------------------------
extern "C" void kernel_launch(void* const* d_in, const int* in_sizes, int n_in,
                              void* d_out, int out_size, void* d_ws, size_t ws_size,
                              hipStream_t stream)
{
    const float* x_u    = (const float*)d_in[0];
    const float* x_v    = (const float*)d_in[1];
    const float* x_f    = (const float*)d_in[2];
    const float* W_u_uv = (const float*)d_in[3];
    const float* W_v_uv = (const float*)d_in[4];
    const float* W_f2u  = (const float*)d_in[5];
    const float* W_f2v  = (const float*)d_in[6];
    const float* W_u2f  = (const float*)d_in[7];
    const float* W_v2f  = (const float*)d_in[8];

    const int* rows_[6] = {(const int*)d_in[9],  (const int*)d_in[12],
                           (const int*)d_in[15], (const int*)d_in[18],
                           (const int*)d_in[21], (const int*)d_in[24]};
    const int* cols_[6] = {(const int*)d_in[10], (const int*)d_in[13],
                           (const int*)d_in[16], (const int*)d_in[19],
                           (const int*)d_in[22], (const int*)d_in[25]};
    const float* vals_[6] = {(const float*)d_in[11], (const float*)d_in[14],
                             (const float*)d_in[17], (const float*)d_in[20],
                             (const float*)d_in[23], (const float*)d_in[26]};

    const int NU = in_sizes[0] / TDIM;
    const int NV = in_sizes[1] / TDIM;
    const int NF = in_sizes[2] / TDIM;
    const int E_[6] = {in_sizes[9], in_sizes[12], in_sizes[15],
                       in_sizes[18], in_sizes[21], in_sizes[24]};

    const int nbU = (NU + 255) >> 8;
    const int nbV = (NV + 255) >> 8;
    const int nbF = (NF + 63) >> 6;
    const int NB  = nbU + nbV + nbF;
    const int ntot_rows = NU + NV + NF;

    // u: rel0 uv (A=tmp_v), rel2 uf (B=f2u)
    // v: rel1 vu (A=tmp_u), rel3 vf (B=f2v)
    // f: rel4 fu (A=u2f),  rel5 fv (B=v2f)
    const int boff_[6]  = {0, nbU, 0, nbU, nbU + nbV, nbU + nbV};
    const int shift_[6] = {8, 8, 8, 8, 6, 6};
    const int sflag_[6] = {0, 0, 1, 1, 0, 1};

    size_t etot = 0;
    for (int r = 0; r < 6; ++r) etot += (size_t)E_[r];

    // ---- relation pack / chunk map ----
    RelPack P;
    int nchunks = 0;
    for (int r = 0; r < 6; ++r) {
        P.r[r].rows = rows_[r]; P.r[r].cols = cols_[r]; P.r[r].vals = vals_[r];
        P.r[r].n = E_[r]; P.r[r].chunk0 = nchunks;
        P.r[r].boff = boff_[r]; P.r[r].shift = shift_[r]; P.r[r].srcflag = sflag_[r];
        nchunks += (E_[r] + EPB - 1) / EPB;
    }

    // ---- workspace ----
    char* wsb = (char*)d_ws;
    size_t o = 0;
    auto alloc = [&](size_t bytes) {
        char* p = wsb + o;
        o = (o + bytes + 15) & ~(size_t)15;
        return p;
    };
    unsigned short* tmp_u = (unsigned short*)alloc((size_t)NU * TDIM * 2);
    unsigned short* u2f   = (unsigned short*)alloc((size_t)NU * TDIM * 2);
    unsigned short* tmp_v = (unsigned short*)alloc((size_t)NV * TDIM * 2);
    unsigned short* v2f   = (unsigned short*)alloc((size_t)NV * TDIM * 2);
    unsigned short* f2u   = (unsigned short*)alloc((size_t)NF * TDIM * 2);
    unsigned short* f2v   = (unsigned short*)alloc((size_t)NF * TDIM * 2);
    int* chunkCnt    = (int*)alloc((size_t)nchunks * NB * 4);
    int* bucketTotal = (int*)alloc((size_t)NB * 4);
    int* bbase       = (int*)alloc((size_t)(NB + 1) * 4);
    int* p2          = (int*)alloc((size_t)(2 * ntot_rows + 1) * 4);
    unsigned short* key2 = (unsigned short*)alloc(etot * 2);
    unsigned* payload    = (unsigned*)alloc(etot * 4);
    unsigned* arena      = (unsigned*)alloc(etot * 4);
    (void)ws_size;

    // ---- fused transforms ----
    TPack T;
    T.X[0] = x_u; T.W1[0] = W_u_uv; T.W2[0] = W_u2f; T.Y1[0] = tmp_u; T.Y2[0] = u2f; T.N[0] = NU;
    T.X[1] = x_v; T.W1[1] = W_v_uv; T.W2[1] = W_v2f; T.Y1[1] = tmp_v; T.Y2[1] = v2f; T.N[1] = NV;
    T.X[2] = x_f; T.W1[2] = W_f2u;  T.W2[2] = W_f2v; T.Y1[2] = f2u;  T.Y2[2] = f2v; T.N[2] = NF;
    T.c0[0] = 0;
    T.c0[1] = (NU + 63) / 64;
    T.c0[2] = T.c0[1] + (NV + 63) / 64;
    const int tchunks = T.c0[2] + (NF + 63) / 64;
    transform_fused_kernel<<<tchunks, 256, 0, stream>>>(T);

    // ---- sort pipeline ----
    bhist_kernel<<<nchunks, 512, 0, stream>>>(P, chunkCnt, NB);
    chunkscan_kernel<<<NB, 256, 0, stream>>>(chunkCnt, bucketTotal, NB, nchunks);
    bscan_kernel<<<1, 256, 0, stream>>>(bucketTotal, bbase, NB);
    bucketize_kernel<<<nchunks, 512, 0, stream>>>(P, bbase, chunkCnt, key2, payload, NB);
    finesort_kernel<<<NB, 512, 0, stream>>>(
        key2, payload, bbase, p2, arena, nbU, nbV, NU, NV, NF, NB, ntot_rows);

    // ---- gather (+ReLU) ----
    GatherPack G;
    G.srcA[0] = (const unsigned*)tmp_v; G.srcB[0] = (const unsigned*)f2u;
    G.srcA[1] = (const unsigned*)tmp_u; G.srcB[1] = (const unsigned*)f2v;
    G.srcA[2] = (const unsigned*)u2f;   G.srcB[2] = (const unsigned*)v2f;
    G.n0 = NU; G.n1 = NU + NV;

    gather_all_kernel<<<(ntot_rows + 3) / 4, 256, 0, stream>>>(
        p2, arena, G, (float*)d_out, ntot_rows);
}

// Round 9
// 589.717 us; speedup vs baseline: 1.1601x; 1.1601x over previous
//
#include <hip/hip_runtime.h>

// ---------------------------------------------------------------------------
// HeteroTripartiteGCN, round 9: chunk-major records (sequential writes).
//   1) fused transforms (fp32 -> bf16 tables)
//   2) bucketize_cm: block per 16K-edge chunk. LDS 666-bin hist -> LDS scan
//      -> writes records CHUNK-MAJOR, bucket-grouped within the chunk
//      (sequential 128KB segment per block -> ~1x write amplification),
//      plus run directory localStart[chunk][667] and bucketTotal atomics.
//      (replaces r8's bhist + chunkscan + scattered bucketize)
//   3) bscan: 666-entry exclusive scan -> bbase
//   4) finesort: block per bucket; run directory (~215 runs) cached in LDS;
//      count pass + scatter pass over the bucket's runs; row-sorted 4B arena
//      segment (single-block L2-hot) + global rowptr p2
//   5) gather: wave/row, half-wave/edge, bf16 pairs, fused ReLU (unchanged)
// d_out: [msg_u | msg_v | msg_f] fp32, every row written exactly once.
// ---------------------------------------------------------------------------

#define TDIM 64
#define EPB  16384

struct Rel {
    const int* rows; const int* cols; const float* vals;
    int n, chunk0, boff, shift, srcflag, eoff;
};
struct RelPack { Rel r[6]; };

struct TPack {
    const float* X[3]; const float* W1[3]; const float* W2[3];
    unsigned short* Y1[3]; unsigned short* Y2[3];
    int N[3]; int c0[3];
};

struct FSPack {              // per output type: the two source relations
    int c0A[3], cntA[3], offA[3];
    int c0B[3], cntB[3], offB[3];
};

struct GatherPack {
    const unsigned* srcA[3]; const unsigned* srcB[3];
    int n0, n1;   // NU, NU+NV
};

__device__ __forceinline__ unsigned short f2bf(float f) {
    union { float f; unsigned u; } c; c.f = f;
    unsigned r = c.u + 0x7FFFu + ((c.u >> 16) & 1u);  // RNE
    return (unsigned short)(r >> 16);
}
__device__ __forceinline__ float bflo(unsigned x) { return __uint_as_float(x << 16); }
__device__ __forceinline__ float bfhi(unsigned x) { return __uint_as_float(x & 0xFFFF0000u); }
__device__ __forceinline__ float pval(unsigned p) {
    return __uint_as_float((p & 0x7FFFu) << 16);     // bf16 val, sign==0
}

// ---------------- fused dense transforms (fp32 in, bf16 out) ----------------
__global__ __launch_bounds__(256) void transform_fused_kernel(TPack T)
{
    __shared__ float xsT[64 * 68];
    __shared__ float w1s[64 * 64];
    __shared__ float w2s[64 * 64];

    int t = 0;
    if ((int)blockIdx.x >= T.c0[1]) t = 1;
    if ((int)blockIdx.x >= T.c0[2]) t = 2;
    const float* __restrict__ X  = T.X[t];
    const float* __restrict__ W1 = T.W1[t];
    const float* __restrict__ W2 = T.W2[t];
    unsigned short* __restrict__ Y1 = T.Y1[t];
    unsigned short* __restrict__ Y2 = T.Y2[t];
    const int N    = T.N[t];
    const int row0 = (blockIdx.x - T.c0[t]) * 64;
    const int tid  = threadIdx.x;

    for (int i = tid * 4; i < 4096; i += 256 * 4) {
        *(float4*)&w1s[i] = *(const float4*)&W1[i];
        *(float4*)&w2s[i] = *(const float4*)&W2[i];
    }
    {
        const int r  = tid >> 2;
        const int c0 = (tid & 3) * 16;
        const int gr = row0 + r;
        #pragma unroll
        for (int cc = 0; cc < 16; cc += 4) {
            const int c = c0 + cc;
            float4 v = make_float4(0.f, 0.f, 0.f, 0.f);
            if (gr < N) v = *(const float4*)&X[(size_t)gr * TDIM + c];
            xsT[(c + 0) * 68 + r] = v.x;
            xsT[(c + 1) * 68 + r] = v.y;
            xsT[(c + 2) * 68 + r] = v.z;
            xsT[(c + 3) * 68 + r] = v.w;
        }
    }
    __syncthreads();

    const int tx = tid & 15;
    const int ty = tid >> 4;
    float a1[4][4] = {{0.f}}, a2[4][4] = {{0.f}};

    #pragma unroll 8
    for (int k = 0; k < 64; ++k) {
        const float4 xv = *(const float4*)&xsT[k * 68 + ty * 4];
        const float4 w1 = *(const float4*)&w1s[k * 64 + tx * 4];
        const float4 w2 = *(const float4*)&w2s[k * 64 + tx * 4];
        const float xr[4] = {xv.x, xv.y, xv.z, xv.w};
        const float c1[4] = {w1.x, w1.y, w1.z, w1.w};
        const float c2[4] = {w2.x, w2.y, w2.z, w2.w};
        #pragma unroll
        for (int r = 0; r < 4; ++r)
            #pragma unroll
            for (int c = 0; c < 4; ++c) {
                a1[r][c] = fmaf(xr[r], c1[c], a1[r][c]);
                a2[r][c] = fmaf(xr[r], c2[c], a2[r][c]);
            }
    }
    #pragma unroll
    for (int r = 0; r < 4; ++r) {
        const int gr = row0 + ty * 4 + r;
        if (gr < N) {
            ushort4 o1, o2;
            o1.x = f2bf(a1[r][0]); o1.y = f2bf(a1[r][1]);
            o1.z = f2bf(a1[r][2]); o1.w = f2bf(a1[r][3]);
            o2.x = f2bf(a2[r][0]); o2.y = f2bf(a2[r][1]);
            o2.z = f2bf(a2[r][2]); o2.w = f2bf(a2[r][3]);
            ((ushort4*)Y1)[(size_t)gr * 16 + tx] = o1;
            ((ushort4*)Y2)[(size_t)gr * 16 + tx] = o2;
        }
    }
}

__device__ __forceinline__ int find_rel(const RelPack& P, int chunk) {
    int ri = 0;
    if (chunk >= P.r[1].chunk0) ri = 1;
    if (chunk >= P.r[2].chunk0) ri = 2;
    if (chunk >= P.r[3].chunk0) ri = 3;
    if (chunk >= P.r[4].chunk0) ri = 4;
    if (chunk >= P.r[5].chunk0) ri = 5;
    return ri;
}

// ---------------- bucketize, chunk-major ----------------
// Block per chunk: LDS hist -> LDS scan -> sequential record writes into the
// chunk's own segment, grouped by bucket. Also emits run directory and
// bucket totals. Record: x = col | rel<<31, y = row_local<<16 | bf16(val).
__global__ __launch_bounds__(512) void bucketize_cm_kernel(
    RelPack P, uint2* __restrict__ recs, int* __restrict__ localStart,
    int* __restrict__ bucketTotal, int NB)
{
    __shared__ int cnt[1024];
    __shared__ int sh[512];

    const int tid   = threadIdx.x;
    const int chunk = blockIdx.x;
    for (int t = tid; t < NB; t += 512) cnt[t] = 0;
    __syncthreads();

    const int ri = find_rel(P, chunk);
    const Rel M = P.r[ri];
    const int i0    = (chunk - M.chunk0) * EPB;
    const int rbase = M.eoff + i0;          // chunk's record segment base

    // pass A: LDS histogram of destination buckets
    #pragma unroll
    for (int k = 0; k < EPB / 512; ++k) {
        const int i = i0 + tid + k * 512;
        if (i < M.n) atomicAdd(&cnt[M.boff + (M.rows[i] >> M.shift)], 1);
    }
    __syncthreads();

    // bucket totals + LDS exclusive scan (2 bins/thread)
    const int i0b = 2 * tid, i1b = 2 * tid + 1;
    const int v0 = (i0b < NB) ? cnt[i0b] : 0;
    const int v1 = (i1b < NB) ? cnt[i1b] : 0;
    if (v0) atomicAdd(&bucketTotal[i0b], v0);
    if (v1) atomicAdd(&bucketTotal[i1b], v1);
    sh[tid] = v0 + v1;
    __syncthreads();
    for (int off = 1; off < 512; off <<= 1) {
        const int x = (tid >= off) ? sh[tid - off] : 0;
        __syncthreads();
        sh[tid] += x;
        __syncthreads();
    }
    const int base0 = tid ? sh[tid - 1] : 0;

    // run directory + cursors
    const size_t lb = (size_t)chunk * (NB + 1);
    if (i0b < NB) localStart[lb + i0b] = base0;
    if (i1b < NB) localStart[lb + i1b] = base0 + v0;
    if (i0b == NB)      localStart[lb + NB] = base0;
    else if (i1b == NB) localStart[lb + NB] = base0 + v0;
    if (i0b < NB) cnt[i0b] = base0;
    if (i1b < NB) cnt[i1b] = base0 + v0;
    __syncthreads();

    // pass B: sequential-segment record writes (rows re-read L2-hot)
    const unsigned flag = (unsigned)M.srcflag << 31;
    const int mask = (1 << M.shift) - 1;
    #pragma unroll
    for (int k = 0; k < EPB / 512; ++k) {
        const int i = i0 + tid + k * 512;
        if (i < M.n) {
            const int row = M.rows[i];
            const int b   = M.boff + (row >> M.shift);
            const int pos = atomicAdd(&cnt[b], 1);
            uint2 rec;
            rec.x = (unsigned)M.cols[i] | flag;
            rec.y = ((unsigned)(row & mask) << 16) | (unsigned)f2bf(M.vals[i]);
            recs[rbase + pos] = rec;
        }
    }
}

// ---------------- bscan: 666-entry exclusive scan ----------------
__global__ __launch_bounds__(256) void bscan_kernel(
    const int* __restrict__ bucketTotal, int* __restrict__ bbase, int NB)
{
    __shared__ int sh[256];
    __shared__ int carry;
    const int t = threadIdx.x;
    if (t == 0) carry = 0;
    __syncthreads();
    for (int b0 = 0; b0 < NB; b0 += 256) {
        const int idx = b0 + t;
        const int c = (idx < NB) ? bucketTotal[idx] : 0;
        sh[t] = c;
        __syncthreads();
        for (int off = 1; off < 256; off <<= 1) {
            const int x = (t >= off) ? sh[t - off] : 0;
            __syncthreads();
            sh[t] += x;
            __syncthreads();
        }
        const int cbase = carry;
        if (idx < NB) bbase[idx] = cbase + sh[t] - c;
        __syncthreads();
        if (t == 0) carry = cbase + sh[255];
        __syncthreads();
    }
    if (t == 0) bbase[NB] = carry;
}

// ---------------- finesort: block per bucket over its runs ----------------
__global__ __launch_bounds__(512) void finesort_kernel(
    const uint2* __restrict__ recs, const int* __restrict__ localStart,
    const int* __restrict__ bbase, FSPack F, int* __restrict__ p2,
    unsigned* __restrict__ arena,
    int nbU, int nbV, int NU, int NV, int NF, int NB, int ntot_rows)
{
    __shared__ int cnt[512];
    __shared__ int sh[512];
    __shared__ int runS[256], runE[256], runB[256];

    const int b   = blockIdx.x;
    const int tid = threadIdx.x;

    int t, lb, rowbase;
    if (b < nbU)              { t = 0; lb = b;              rowbase = 0; }
    else if (b < nbU + nbV)   { t = 1; lb = b - nbU;        rowbase = NU; }
    else                      { t = 2; lb = b - nbU - nbV;  rowbase = NU + NV; }
    const int shift     = (t == 2) ? 6 : 8;
    const int Ntype     = (t == 0) ? NU : (t == 1) ? NV : NF;
    const int row_start = lb << shift;
    const int nrows     = min(1 << shift, Ntype - row_start);
    const int nbins     = (1 << shift) * 2;
    const int grow0     = rowbase + row_start;

    const int nA = F.cntA[t], nB_ = F.cntB[t];
    const int nRuns = nA + nB_;

    // load run directory into LDS
    if (tid < nRuns) {
        int c, base;
        if (tid < nA) { c = F.c0A[t] + tid;        base = F.offA[t] + tid * EPB; }
        else          { int k = tid - nA;
                        c = F.c0B[t] + k;          base = F.offB[t] + k * EPB; }
        const size_t lbi = (size_t)c * (NB + 1) + b;
        runS[tid] = base + localStart[lbi];
        runE[tid] = base + localStart[lbi + 1];
        runB[tid] = 0;
    }
    if (tid < nbins) cnt[tid] = 0;
    __syncthreads();

    const int s = bbase[b];
    const int e = bbase[b + 1];
    const int wave = tid >> 6;
    const int lane = tid & 63;

    // pass 1: count (row_local, rel)
    for (int ridx = wave; ridx < nRuns; ridx += 8) {
        const int rs = runS[ridx], re = runE[ridx];
        for (int j = rs + lane; j < re; j += 64) {
            const uint2 r = recs[j];
            const int bin = (int)((r.y >> 16) << 1) | (int)(r.x >> 31);
            atomicAdd(&cnt[bin], 1);
        }
    }
    __syncthreads();

    // exclusive scan over nbins (<=512)
    const int v = (tid < nbins) ? cnt[tid] : 0;
    sh[tid] = v;
    __syncthreads();
    for (int off = 1; off < 512; off <<= 1) {
        const int x = (tid >= off) ? sh[tid - off] : 0;
        __syncthreads();
        sh[tid] += x;
        __syncthreads();
    }
    const int excl = sh[tid] - v;
    if (tid < nbins) cnt[tid] = excl;          // cursors
    if (tid < nrows * 2) p2[2 * grow0 + tid] = s + excl;
    if (b == NB - 1 && tid == 0) p2[2 * ntot_rows] = e;
    __syncthreads();

    // pass 2: scatter packed payload into bucket arena segment (L2-hot)
    for (int ridx = wave; ridx < nRuns; ridx += 8) {
        const int rs = runS[ridx], re = runE[ridx];
        for (int j = rs + lane; j < re; j += 64) {
            const uint2 r = recs[j];
            const int bin = (int)((r.y >> 16) << 1) | (int)(r.x >> 31);
            const int pos = s + atomicAdd(&cnt[bin], 1);
            arena[pos] = ((r.x & 0x7FFFFFFFu) << 15) | (r.y & 0x7FFFu);
        }
    }
    (void)runB;
}

// ---------------- gather: wave per row, half-wave per edge, ReLU -----------
__global__ __launch_bounds__(256) void gather_all_kernel(
    const int* __restrict__ p2, const unsigned* __restrict__ arena,
    GatherPack G, float* __restrict__ out, int nrow_total)
{
    const int wid  = (blockIdx.x * 256 + threadIdx.x) >> 6;
    const int lane = threadIdx.x & 63;
    const int half = lane >> 5;
    const int sub  = lane & 31;
    if (wid >= nrow_total) return;

    int seg = 0;
    if (wid >= G.n1)      seg = 2;
    else if (wid >= G.n0) seg = 1;

    const int pa = p2[2 * wid];
    const int pm = p2[2 * wid + 1];
    const int pe = p2[2 * wid + 2];

    float accx = 0.f, accy = 0.f;

    #pragma unroll
    for (int hh = 0; hh < 2; ++hh) {
        const unsigned* __restrict__ src = hh ? G.srcB[seg] : G.srcA[seg];
        const int s = hh ? pm : pa;
        const int e = hh ? pe : pm;
        int j = s;
        for (; j + 8 <= e; j += 8) {           // 8 edges: 4 per half-wave
            unsigned cv[4], x[4];
            #pragma unroll
            for (int q = 0; q < 4; ++q) cv[q] = arena[j + 2 * q + half];
            #pragma unroll
            for (int q = 0; q < 4; ++q)
                x[q] = src[(size_t)(cv[q] >> 15) * 32 + sub];
            #pragma unroll
            for (int q = 0; q < 4; ++q) {
                const float w = pval(cv[q]);
                accx = fmaf(w, bflo(x[q]), accx);
                accy = fmaf(w, bfhi(x[q]), accy);
            }
        }
        for (; j + 2 <= e; j += 2) {
            const unsigned cv = arena[j + half];
            const unsigned x  = src[(size_t)(cv >> 15) * 32 + sub];
            const float w = pval(cv);
            accx = fmaf(w, bflo(x), accx);
            accy = fmaf(w, bfhi(x), accy);
        }
        if (half == 0 && j < e) {
            const unsigned cv = arena[j];
            const unsigned x  = src[(size_t)(cv >> 15) * 32 + sub];
            const float w = pval(cv);
            accx = fmaf(w, bflo(x), accx);
            accy = fmaf(w, bfhi(x), accy);
        }
    }

    accx += __shfl_xor(accx, 32, 64);
    accy += __shfl_xor(accy, 32, 64);
    if (half == 0) {
        float2 o = make_float2(fmaxf(accx, 0.f), fmaxf(accy, 0.f));
        ((float2*)out)[(size_t)wid * 32 + sub] = o;
    }
}

// ---------------------------------------------------------------------------
extern "C" void kernel_launch(void* const* d_in, const int* in_sizes, int n_in,
                              void* d_out, int out_size, void* d_ws, size_t ws_size,
                              hipStream_t stream)
{
    const float* x_u    = (const float*)d_in[0];
    const float* x_v    = (const float*)d_in[1];
    const float* x_f    = (const float*)d_in[2];
    const float* W_u_uv = (const float*)d_in[3];
    const float* W_v_uv = (const float*)d_in[4];
    const float* W_f2u  = (const float*)d_in[5];
    const float* W_f2v  = (const float*)d_in[6];
    const float* W_u2f  = (const float*)d_in[7];
    const float* W_v2f  = (const float*)d_in[8];

    const int* rows_[6] = {(const int*)d_in[9],  (const int*)d_in[12],
                           (const int*)d_in[15], (const int*)d_in[18],
                           (const int*)d_in[21], (const int*)d_in[24]};
    const int* cols_[6] = {(const int*)d_in[10], (const int*)d_in[13],
                           (const int*)d_in[16], (const int*)d_in[19],
                           (const int*)d_in[22], (const int*)d_in[25]};
    const float* vals_[6] = {(const float*)d_in[11], (const float*)d_in[14],
                             (const float*)d_in[17], (const float*)d_in[20],
                             (const float*)d_in[23], (const float*)d_in[26]};

    const int NU = in_sizes[0] / TDIM;
    const int NV = in_sizes[1] / TDIM;
    const int NF = in_sizes[2] / TDIM;
    const int E_[6] = {in_sizes[9], in_sizes[12], in_sizes[15],
                       in_sizes[18], in_sizes[21], in_sizes[24]};

    const int nbU = (NU + 255) >> 8;
    const int nbV = (NV + 255) >> 8;
    const int nbF = (NF + 63) >> 6;
    const int NB  = nbU + nbV + nbF;
    const int ntot_rows = NU + NV + NF;

    // u: rel0 uv (A=tmp_v), rel2 uf (B=f2u)
    // v: rel1 vu (A=tmp_u), rel3 vf (B=f2v)
    // f: rel4 fu (A=u2f),  rel5 fv (B=v2f)
    const int boff_[6]  = {0, nbU, 0, nbU, nbU + nbV, nbU + nbV};
    const int shift_[6] = {8, 8, 8, 8, 6, 6};
    const int sflag_[6] = {0, 0, 1, 1, 0, 1};

    size_t etot = 0;
    int eoff_[6];
    for (int r = 0; r < 6; ++r) { eoff_[r] = (int)etot; etot += (size_t)E_[r]; }

    // ---- relation pack / chunk map ----
    RelPack P;
    int nchunks = 0;
    int relchunks[6];
    for (int r = 0; r < 6; ++r) {
        P.r[r].rows = rows_[r]; P.r[r].cols = cols_[r]; P.r[r].vals = vals_[r];
        P.r[r].n = E_[r]; P.r[r].chunk0 = nchunks;
        P.r[r].boff = boff_[r]; P.r[r].shift = shift_[r]; P.r[r].srcflag = sflag_[r];
        P.r[r].eoff = eoff_[r];
        relchunks[r] = (E_[r] + EPB - 1) / EPB;
        nchunks += relchunks[r];
    }

    // ---- workspace ----
    char* wsb = (char*)d_ws;
    size_t o = 0;
    auto alloc = [&](size_t bytes) {
        char* p = wsb + o;
        o = (o + bytes + 15) & ~(size_t)15;
        return p;
    };
    unsigned short* tmp_u = (unsigned short*)alloc((size_t)NU * TDIM * 2);
    unsigned short* u2f   = (unsigned short*)alloc((size_t)NU * TDIM * 2);
    unsigned short* tmp_v = (unsigned short*)alloc((size_t)NV * TDIM * 2);
    unsigned short* v2f   = (unsigned short*)alloc((size_t)NV * TDIM * 2);
    unsigned short* f2u   = (unsigned short*)alloc((size_t)NF * TDIM * 2);
    unsigned short* f2v   = (unsigned short*)alloc((size_t)NF * TDIM * 2);
    int* localStart  = (int*)alloc((size_t)nchunks * (NB + 1) * 4);
    int* bucketTotal = (int*)alloc((size_t)NB * 4);
    int* bbase       = (int*)alloc((size_t)(NB + 1) * 4);
    int* p2          = (int*)alloc((size_t)(2 * ntot_rows + 1) * 4);
    uint2* recs      = (uint2*)alloc(etot * 8);
    unsigned* arena  = (unsigned*)alloc(etot * 4);
    (void)ws_size;

    // ---- fused transforms ----
    TPack T;
    T.X[0] = x_u; T.W1[0] = W_u_uv; T.W2[0] = W_u2f; T.Y1[0] = tmp_u; T.Y2[0] = u2f; T.N[0] = NU;
    T.X[1] = x_v; T.W1[1] = W_v_uv; T.W2[1] = W_v2f; T.Y1[1] = tmp_v; T.Y2[1] = v2f; T.N[1] = NV;
    T.X[2] = x_f; T.W1[2] = W_f2u;  T.W2[2] = W_f2v; T.Y1[2] = f2u;  T.Y2[2] = f2v; T.N[2] = NF;
    T.c0[0] = 0;
    T.c0[1] = (NU + 63) / 64;
    T.c0[2] = T.c0[1] + (NV + 63) / 64;
    const int tchunks = T.c0[2] + (NF + 63) / 64;
    transform_fused_kernel<<<tchunks, 256, 0, stream>>>(T);

    // ---- sort pipeline ----
    hipMemsetAsync(bucketTotal, 0, (size_t)NB * sizeof(int), stream);
    bucketize_cm_kernel<<<nchunks, 512, 0, stream>>>(P, recs, localStart, bucketTotal, NB);
    bscan_kernel<<<1, 256, 0, stream>>>(bucketTotal, bbase, NB);

    FSPack F;
    const int Arel[3] = {0, 1, 4}, Brel[3] = {2, 3, 5};
    for (int t = 0; t < 3; ++t) {
        F.c0A[t] = P.r[Arel[t]].chunk0; F.cntA[t] = relchunks[Arel[t]]; F.offA[t] = eoff_[Arel[t]];
        F.c0B[t] = P.r[Brel[t]].chunk0; F.cntB[t] = relchunks[Brel[t]]; F.offB[t] = eoff_[Brel[t]];
    }
    finesort_kernel<<<NB, 512, 0, stream>>>(
        recs, localStart, bbase, F, p2, arena, nbU, nbV, NU, NV, NF, NB, ntot_rows);

    // ---- gather (+ReLU) ----
    GatherPack G;
    G.srcA[0] = (const unsigned*)tmp_v; G.srcB[0] = (const unsigned*)f2u;
    G.srcA[1] = (const unsigned*)tmp_u; G.srcB[1] = (const unsigned*)f2v;
    G.srcA[2] = (const unsigned*)u2f;   G.srcB[2] = (const unsigned*)v2f;
    G.n0 = NU; G.n1 = NU + NV;

    gather_all_kernel<<<(ntot_rows + 3) / 4, 256, 0, stream>>>(
        p2, arena, G, (float*)d_out, ntot_rows);
}